// Round 7
// baseline (804.802 us; speedup 1.0000x reference)
//
#include <hip/hip_runtime.h>
#include <hip/hip_bf16.h>
#include <cfloat>

#define BATCH 4
#define DIMC 1792
#define HWSZ 3136
#define NPROT 3136
#define NPAD 3200           // NPROT padded to a multiple of 128
#define MROWS 12544
#define NPT2 25             // NPAD/128 column tiles in gemm2

typedef unsigned short u16;
typedef unsigned int u32;
using bf16x8 = __attribute__((ext_vector_type(8))) short;
using f32x4  = __attribute__((ext_vector_type(4))) float;

__device__ __forceinline__ float bf2f(u32 u) { return __uint_as_float(u << 16); }
__device__ __forceinline__ u16 f2bf(float x) {
    __hip_bfloat16 h = __float2bfloat16(x);   // RNE
    return *reinterpret_cast<u16*>(&h);
}

// async global->LDS, 16B per lane; LDS dest = wave-uniform base + lane*16
__device__ __forceinline__ void gload_lds16(const u16* g, u16* l) {
    __builtin_amdgcn_global_load_lds(
        (const __attribute__((address_space(1))) void*)g,
        (__attribute__((address_space(3))) void*)l, 16, 0, 0);
}

__device__ __forceinline__ void ins3(float v, float& t0, float& t1, float& t2) {
    if (v < t2) {
        if (v < t1) {
            t2 = t1;
            if (v < t0) { t1 = t0; t0 = v; }
            else        { t1 = v; }
        } else {
            t2 = v;
        }
    }
}

// ---- pack p[b][c][hw] (fp32) -> Pbf[r=b*HWSZ+hw][c] (bf16) ----------------
__global__ void pack_p_kernel(const float* __restrict__ p, u16* __restrict__ Pbf) {
    __shared__ float tile[32][33];      // [c_local][hw_local]
    int hw0 = blockIdx.x * 32, c0 = blockIdx.y * 32, b = blockIdx.z;
    int tid = threadIdx.x;
    int tx = tid & 31, ty = tid >> 5;   // load: tx=hw, ty+j = c
#pragma unroll
    for (int j = 0; j < 32; j += 8)
        tile[ty + j][tx] = p[((size_t)(b * DIMC + c0 + ty + j)) * HWSZ + hw0 + tx];
    __syncthreads();
    int hwl = tid >> 3;                 // 0..31
    int c4  = (tid & 7) * 4;            // 0..28
    int r = b * HWSZ + hw0 + hwl;
    ushort4 o;
    o.x = f2bf(tile[c4 + 0][hwl]);
    o.y = f2bf(tile[c4 + 1][hwl]);
    o.z = f2bf(tile[c4 + 2][hwl]);
    o.w = f2bf(tile[c4 + 3][hwl]);
    *(ushort4*)(Pbf + (size_t)r * DIMC + c0 + c4) = o;
}

// ---- cast W[d][c] fp32 -> Wbf[d][c] bf16 ----------------------------------
__global__ void pack_w_kernel(const float* __restrict__ W, u16* __restrict__ Wbf) {
    size_t i = (size_t)(blockIdx.x * 256 + threadIdx.x) * 4;   // exact grid
    float4 v = *(const float4*)(W + i);
    ushort4 o;
    o.x = f2bf(v.x); o.y = f2bf(v.y); o.z = f2bf(v.z); o.w = f2bf(v.w);
    *(ushort4*)(Wbf + i) = o;
}

// ---- pack C[d][j] fp32 -> CTbf[j][d] bf16, fused cn[j] += sum_d C^2 -------
__global__ void pack_c_kernel(const float* __restrict__ C, u16* __restrict__ CTbf,
                              float* __restrict__ cn) {
    __shared__ float tile[32][33];      // [d_local][j_local]
    int j0 = blockIdx.x * 32, d0 = blockIdx.y * 32;
    int tid = threadIdx.x;
    int tx = tid & 31, ty = tid >> 5;
#pragma unroll
    for (int jj = 0; jj < 32; jj += 8)
        tile[ty + jj][tx] = C[(size_t)(d0 + ty + jj) * NPROT + j0 + tx];
    __syncthreads();
    int jl = tid >> 3;                  // 0..31
    int d4 = (tid & 7) * 4;
    float s = 0.f;
    ushort4 o;
    {
        float f0 = tile[d4 + 0][jl], f1 = tile[d4 + 1][jl];
        float f2 = tile[d4 + 2][jl], f3 = tile[d4 + 3][jl];
        o.x = f2bf(f0); o.y = f2bf(f1); o.z = f2bf(f2); o.w = f2bf(f3);
        s = f0 * f0 + f1 * f1 + f2 * f2 + f3 * f3;   // fp32, pre-rounding
    }
    *(ushort4*)(CTbf + (size_t)(j0 + jl) * DIMC + d0 + d4) = o;
    // threads with same jl are 8 consecutive lanes -> butterfly then 1 atomic
#pragma unroll
    for (int off = 1; off < 8; off <<= 1) s += __shfl_xor(s, off);
    if ((tid & 7) == 0) atomicAdd(&cn[j0 + jl], s);
}

// ---- GEMM1: phibf[r][n] = sum_k Pbf[r][k]*Wbf[n][k] + bias[n]; rn fused ---
// m97 structure: 128x128 tile, 4 waves, BK=32, global_load_lds width-16.
// Grid: dim3(r-tiles, n-tiles) -- r fast => co-resident blocks share the
// B(W)-panel in L2 and stream A. (XCD swizzle by r0 thrashed L2: r6 postmortem)
__global__ __launch_bounds__(256) void gemm_bias_kernel(
    const u16* __restrict__ A, const u16* __restrict__ B,
    const float* __restrict__ bias, u16* __restrict__ out, int ldo,
    float* __restrict__ rn)
{
    __shared__ __align__(16) u16 Als[128 * 32];
    __shared__ __align__(16) u16 Bls[128 * 32];
    const int tid  = threadIdx.x;
    const int wid  = tid >> 6;
    const int lane = tid & 63;
    const int r0 = blockIdx.x * 128;
    const int n0 = blockIdx.y * 128;

    const int srow = lane >> 2;
    const int sseg = (lane & 3) * 8;
    const u16* Ag = A + (size_t)(r0 + wid * 32 + srow) * DIMC + sseg;
    const u16* Bg = B + (size_t)(n0 + wid * 32 + srow) * DIMC + sseg;
    u16* AlsW = Als + wid * 1024;
    u16* BlsW = Bls + wid * 1024;

    const int wm = (wid >> 1) * 64;
    const int wn = (wid & 1) * 64;
    const int lrow = lane & 15;
    const int kseg = (lane >> 4) * 8;
    const int rsub = (lane >> 4) * 4;

    f32x4 acc[4][4];
#pragma unroll
    for (int m = 0; m < 4; ++m)
#pragma unroll
        for (int n = 0; n < 4; ++n)
            acc[m][n] = (f32x4){0.f, 0.f, 0.f, 0.f};

    for (int k0 = 0; k0 < DIMC; k0 += 32) {
        gload_lds16(Ag + k0,                      AlsW);
        gload_lds16(Ag + (size_t)16 * DIMC + k0,  AlsW + 512);
        gload_lds16(Bg + k0,                      BlsW);
        gload_lds16(Bg + (size_t)16 * DIMC + k0,  BlsW + 512);
        __syncthreads();
        bf16x8 af[4], bv[4];
#pragma unroll
        for (int m = 0; m < 4; ++m)
            af[m] = *(const bf16x8*)(Als + (wm + m * 16 + lrow) * 32 + kseg);
#pragma unroll
        for (int n = 0; n < 4; ++n)
            bv[n] = *(const bf16x8*)(Bls + (wn + n * 16 + lrow) * 32 + kseg);
#pragma unroll
        for (int m = 0; m < 4; ++m)
#pragma unroll
            for (int n = 0; n < 4; ++n)
                acc[m][n] = __builtin_amdgcn_mfma_f32_16x16x32_bf16(
                    af[m], bv[n], acc[m][n], 0, 0, 0);
        __syncthreads();
    }

    // epilogue: bias add, bf16 store, fused rn += sum(phi^2)
    float bsv[4];
#pragma unroll
    for (int n = 0; n < 4; ++n) bsv[n] = bias[n0 + wn + n * 16 + lrow];
#pragma unroll
    for (int m = 0; m < 4; ++m) {
        float rsum[4] = {0.f, 0.f, 0.f, 0.f};
#pragma unroll
        for (int n = 0; n < 4; ++n) {
            int col = n0 + wn + n * 16 + lrow;
            f32x4 v = acc[m][n];
#pragma unroll
            for (int i = 0; i < 4; ++i) {
                float f = v[i] + bsv[n];
                rsum[i] += f * f;
                int row = r0 + wm + m * 16 + rsub + i;
                out[(size_t)row * ldo + col] = f2bf(f);
            }
        }
#pragma unroll
        for (int i = 0; i < 4; ++i) {
            float s = rsum[i];
#pragma unroll
            for (int off = 1; off < 16; off <<= 1) s += __shfl_xor(s, off);
            if (lrow == 0)
                atomicAdd(&rn[r0 + wm + m * 16 + rsub + i], s);
        }
    }
}

// ---- GEMM2 + fused top-3: ptop[row][pt][3] partial mins -------------------
// t[row][col] = cn[col] - 2 * sum_k phibf[row][k]*CTbf[col][k]
// Grid: dim3(r-tiles, pt) -- r fast => co-resident blocks share the C-panel.
__global__ __launch_bounds__(256) void gemm_top3_kernel(
    const u16* __restrict__ A, const u16* __restrict__ B,
    const float* __restrict__ cn, float* __restrict__ ptop)
{
    __shared__ __align__(16) u16 Als[128 * 32];
    __shared__ __align__(16) u16 Bls[128 * 32];
    __shared__ float red[128][2][3];
    const int tid  = threadIdx.x;
    const int wid  = tid >> 6;
    const int lane = tid & 63;
    const int r0 = blockIdx.x * 128;
    const int pt = blockIdx.y;
    const int n0 = pt * 128;

    const int srow = lane >> 2;
    const int sseg = (lane & 3) * 8;
    const u16* Ag = A + (size_t)(r0 + wid * 32 + srow) * DIMC + sseg;
    const u16* Bg = B + (size_t)(n0 + wid * 32 + srow) * DIMC + sseg;
    u16* AlsW = Als + wid * 1024;
    u16* BlsW = Bls + wid * 1024;

    const int wm = (wid >> 1) * 64;
    const int wn = (wid & 1) * 64;
    const int lrow = lane & 15;
    const int kseg = (lane >> 4) * 8;
    const int rsub = (lane >> 4) * 4;

    f32x4 acc[4][4];
#pragma unroll
    for (int m = 0; m < 4; ++m)
#pragma unroll
        for (int n = 0; n < 4; ++n)
            acc[m][n] = (f32x4){0.f, 0.f, 0.f, 0.f};

    for (int k0 = 0; k0 < DIMC; k0 += 32) {
        gload_lds16(Ag + k0,                      AlsW);
        gload_lds16(Ag + (size_t)16 * DIMC + k0,  AlsW + 512);
        gload_lds16(Bg + k0,                      BlsW);
        gload_lds16(Bg + (size_t)16 * DIMC + k0,  BlsW + 512);
        __syncthreads();
        bf16x8 af[4], bv[4];
#pragma unroll
        for (int m = 0; m < 4; ++m)
            af[m] = *(const bf16x8*)(Als + (wm + m * 16 + lrow) * 32 + kseg);
#pragma unroll
        for (int n = 0; n < 4; ++n)
            bv[n] = *(const bf16x8*)(Bls + (wn + n * 16 + lrow) * 32 + kseg);
#pragma unroll
        for (int m = 0; m < 4; ++m)
#pragma unroll
            for (int n = 0; n < 4; ++n)
                acc[m][n] = __builtin_amdgcn_mfma_f32_16x16x32_bf16(
                    af[m], bv[n], acc[m][n], 0, 0, 0);
        __syncthreads();
    }

    // fused epilogue: per-lane 4-col top3 per row, 16-lane-group shfl merge,
    // cross-wave merge via 3KB LDS, block-partial -> ptop[row][pt][3].
    float cnv[4];
#pragma unroll
    for (int n = 0; n < 4; ++n) {
        int col = n0 + wn + n * 16 + lrow;
        cnv[n] = (col < NPROT) ? cn[col] : FLT_MAX;   // padded cols never win
    }
#pragma unroll
    for (int m = 0; m < 4; ++m) {
#pragma unroll
        for (int i = 0; i < 4; ++i) {
            float t0 = FLT_MAX, t1 = FLT_MAX, t2 = FLT_MAX;
#pragma unroll
            for (int n = 0; n < 4; ++n)
                ins3(cnv[n] - 2.f * acc[m][n][i], t0, t1, t2);
#pragma unroll
            for (int off = 1; off < 16; off <<= 1) {
                float s0 = __shfl_xor(t0, off);
                float s1 = __shfl_xor(t1, off);
                float s2 = __shfl_xor(t2, off);
                ins3(s0, t0, t1, t2);
                ins3(s1, t0, t1, t2);
                ins3(s2, t0, t1, t2);
            }
            if (lrow == 0) {
                int row = wm + m * 16 + rsub + i;      // 0..127 in block
                red[row][wid & 1][0] = t0;
                red[row][wid & 1][1] = t1;
                red[row][wid & 1][2] = t2;
            }
        }
    }
    __syncthreads();
    if (tid < 128) {
        float t0 = red[tid][0][0], t1 = red[tid][0][1], t2 = red[tid][0][2];
        ins3(red[tid][1][0], t0, t1, t2);
        ins3(red[tid][1][1], t0, t1, t2);
        ins3(red[tid][1][2], t0, t1, t2);
        size_t base = ((size_t)(r0 + tid) * NPT2 + pt) * 3;
        ptop[base + 0] = t0;
        ptop[base + 1] = t1;
        ptop[base + 2] = t2;
    }
}

// ---- final: merge 25x3 partials + sqrt + softmin --------------------------
__global__ void final_kernel(const float* __restrict__ ptop,
                             const float* __restrict__ rn,
                             float* __restrict__ out) {
    int r = blockIdx.x * 256 + threadIdx.x;   // exact: MROWS/256 = 49
    float t0 = FLT_MAX, t1 = FLT_MAX, t2 = FLT_MAX;
    const float* pp = ptop + (size_t)r * NPT2 * 3;
    for (int q = 0; q < NPT2 * 3; ++q) ins3(pp[q], t0, t1, t2);
    float rv = rn[r];
    float d0 = sqrtf(rv + t0), d1 = sqrtf(rv + t1), d2 = sqrtf(rv + t2);
    float w0 = 1.f / (1.f + expf(d0 - d1) + expf(d0 - d2));
    out[r] = w0 * d0;
}

extern "C" void kernel_launch(void* const* d_in, const int* in_sizes, int n_in,
                              void* d_out, int out_size, void* d_ws, size_t ws_size,
                              hipStream_t stream) {
    const float* p    = (const float*)d_in[0];
    const float* W    = (const float*)d_in[1];
    const float* bias = (const float*)d_in[2];
    const float* C    = (const float*)d_in[3];
    float* out = (float*)d_out;

    char* w = (char*)d_ws;
    u16* Pbf   = (u16*)w;  w += (size_t)MROWS * DIMC * 2;   // 45.0 MB
    u16* Wbf   = (u16*)w;  w += (size_t)DIMC * DIMC * 2;    //  6.4 MB
    u16* CTbf  = (u16*)w;  w += (size_t)NPAD * DIMC * 2;    // 11.5 MB
    u16* phibf = (u16*)w;  w += (size_t)MROWS * DIMC * 2;   // 45.0 MB
    float* ptop = (float*)w; w += (size_t)MROWS * NPT2 * 3 * 4;  // 3.8 MB
    float* cn  = (float*)w; w += (size_t)NPROT * 4;
    float* rn  = (float*)w;                                  // total ~112 MB

    // zero the atomic accumulators (cn and rn are adjacent)
    hipMemsetAsync(cn, 0, (NPROT + MROWS) * sizeof(float), stream);

    pack_p_kernel<<<dim3(HWSZ / 32, DIMC / 32, BATCH), 256, 0, stream>>>(p, Pbf);
    pack_w_kernel<<<(DIMC * DIMC / 4) / 256, 256, 0, stream>>>(W, Wbf);
    pack_c_kernel<<<dim3(NPROT / 32, DIMC / 32), 256, 0, stream>>>(C, CTbf, cn);

    gemm_bias_kernel<<<dim3(MROWS / 128, DIMC / 128), 256, 0, stream>>>(
        Pbf, Wbf, bias, phibf, DIMC, rn);
    gemm_top3_kernel<<<dim3(MROWS / 128, NPT2), 256, 0, stream>>>(
        phibf, CTbf, cn, ptop);
    final_kernel<<<MROWS / 256, 256, 0, stream>>>(ptop, rn, out);
}

// Round 9
// 797.668 us; speedup vs baseline: 1.0089x; 1.0089x over previous
//
#include <hip/hip_runtime.h>
#include <hip/hip_bf16.h>
#include <cfloat>

#define BATCH 4
#define DIMC 1792
#define HWSZ 3136
#define NPROT 3136
#define NPAD 3200           // NPROT padded to a multiple of 128
#define MROWS 12544
#define NPT2 25             // NPAD/128 column tiles in gemm2

typedef unsigned short u16;
typedef unsigned int u32;
using bf16x8 = __attribute__((ext_vector_type(8))) short;
using f32x4  = __attribute__((ext_vector_type(4))) float;

__device__ __forceinline__ float bf2f(u32 u) { return __uint_as_float(u << 16); }
__device__ __forceinline__ u16 f2bf(float x) {
    __hip_bfloat16 h = __float2bfloat16(x);   // RNE
    return *reinterpret_cast<u16*>(&h);
}

// async global->LDS, 16B per lane; LDS dest = wave-uniform base + lane*16
__device__ __forceinline__ void gload_lds16(const u16* g, u16* l) {
    __builtin_amdgcn_global_load_lds(
        (const __attribute__((address_space(1))) void*)g,
        (__attribute__((address_space(3))) void*)l, 16, 0, 0);
}

__device__ __forceinline__ void ins3(float v, float& t0, float& t1, float& t2) {
    if (v < t2) {
        if (v < t1) {
            t2 = t1;
            if (v < t0) { t1 = t0; t0 = v; }
            else        { t1 = v; }
        } else {
            t2 = v;
        }
    }
}

// ---- pack p[b][c][hw] (fp32) -> Pbf[r=b*HWSZ+hw][c] (bf16) ----------------
__global__ void pack_p_kernel(const float* __restrict__ p, u16* __restrict__ Pbf) {
    __shared__ float tile[32][33];      // [c_local][hw_local]
    int hw0 = blockIdx.x * 32, c0 = blockIdx.y * 32, b = blockIdx.z;
    int tid = threadIdx.x;
    int tx = tid & 31, ty = tid >> 5;   // load: tx=hw, ty+j = c
#pragma unroll
    for (int j = 0; j < 32; j += 8)
        tile[ty + j][tx] = p[((size_t)(b * DIMC + c0 + ty + j)) * HWSZ + hw0 + tx];
    __syncthreads();
    int hwl = tid >> 3;                 // 0..31
    int c4  = (tid & 7) * 4;            // 0..28
    int r = b * HWSZ + hw0 + hwl;
    ushort4 o;
    o.x = f2bf(tile[c4 + 0][hwl]);
    o.y = f2bf(tile[c4 + 1][hwl]);
    o.z = f2bf(tile[c4 + 2][hwl]);
    o.w = f2bf(tile[c4 + 3][hwl]);
    *(ushort4*)(Pbf + (size_t)r * DIMC + c0 + c4) = o;
}

// ---- cast W[d][c] fp32 -> Wbf[d][c] bf16 ----------------------------------
__global__ void pack_w_kernel(const float* __restrict__ W, u16* __restrict__ Wbf) {
    size_t i = (size_t)(blockIdx.x * 256 + threadIdx.x) * 4;   // exact grid
    float4 v = *(const float4*)(W + i);
    ushort4 o;
    o.x = f2bf(v.x); o.y = f2bf(v.y); o.z = f2bf(v.z); o.w = f2bf(v.w);
    *(ushort4*)(Wbf + i) = o;
}

// ---- pack C[d][j] fp32 -> CTbf[j][d] bf16, fused cn[j] += sum_d C^2 -------
__global__ void pack_c_kernel(const float* __restrict__ C, u16* __restrict__ CTbf,
                              float* __restrict__ cn) {
    __shared__ float tile[32][33];      // [d_local][j_local]
    int j0 = blockIdx.x * 32, d0 = blockIdx.y * 32;
    int tid = threadIdx.x;
    int tx = tid & 31, ty = tid >> 5;
#pragma unroll
    for (int jj = 0; jj < 32; jj += 8)
        tile[ty + jj][tx] = C[(size_t)(d0 + ty + jj) * NPROT + j0 + tx];
    __syncthreads();
    int jl = tid >> 3;                  // 0..31
    int d4 = (tid & 7) * 4;
    float s = 0.f;
    ushort4 o;
    {
        float f0 = tile[d4 + 0][jl], f1 = tile[d4 + 1][jl];
        float f2 = tile[d4 + 2][jl], f3 = tile[d4 + 3][jl];
        o.x = f2bf(f0); o.y = f2bf(f1); o.z = f2bf(f2); o.w = f2bf(f3);
        s = f0 * f0 + f1 * f1 + f2 * f2 + f3 * f3;   // fp32, pre-rounding
    }
    *(ushort4*)(CTbf + (size_t)(j0 + jl) * DIMC + d0 + d4) = o;
    // threads with same jl are 8 consecutive lanes -> butterfly then 1 atomic
#pragma unroll
    for (int off = 1; off < 8; off <<= 1) s += __shfl_xor(s, off);
    if ((tid & 7) == 0) atomicAdd(&cn[j0 + jl], s);
}

// ---- GEMM1: phibf[r][n] = sum_k Pbf[r][k]*Wbf[n][k] + bias[n]; rn fused ---
// m97 structure: 128x128 tile, 4 waves, BK=32, global_load_lds width-16.
__global__ __launch_bounds__(256) void gemm_bias_kernel(
    const u16* __restrict__ A, const u16* __restrict__ B,
    const float* __restrict__ bias, u16* __restrict__ out, int ldo,
    float* __restrict__ rn)
{
    __shared__ __align__(16) u16 Als[128 * 32];
    __shared__ __align__(16) u16 Bls[128 * 32];
    const int tid  = threadIdx.x;
    const int wid  = tid >> 6;
    const int lane = tid & 63;
    const int r0 = blockIdx.x * 128;
    const int n0 = blockIdx.y * 128;

    const int srow = lane >> 2;
    const int sseg = (lane & 3) * 8;
    const u16* Ag = A + (size_t)(r0 + wid * 32 + srow) * DIMC + sseg;
    const u16* Bg = B + (size_t)(n0 + wid * 32 + srow) * DIMC + sseg;
    u16* AlsW = Als + wid * 1024;
    u16* BlsW = Bls + wid * 1024;

    const int wm = (wid >> 1) * 64;
    const int wn = (wid & 1) * 64;
    const int lrow = lane & 15;
    const int kseg = (lane >> 4) * 8;
    const int rsub = (lane >> 4) * 4;

    f32x4 acc[4][4];
#pragma unroll
    for (int m = 0; m < 4; ++m)
#pragma unroll
        for (int n = 0; n < 4; ++n)
            acc[m][n] = (f32x4){0.f, 0.f, 0.f, 0.f};

    for (int k0 = 0; k0 < DIMC; k0 += 32) {
        gload_lds16(Ag + k0,                      AlsW);
        gload_lds16(Ag + (size_t)16 * DIMC + k0,  AlsW + 512);
        gload_lds16(Bg + k0,                      BlsW);
        gload_lds16(Bg + (size_t)16 * DIMC + k0,  BlsW + 512);
        __syncthreads();
        bf16x8 af[4], bv[4];
#pragma unroll
        for (int m = 0; m < 4; ++m)
            af[m] = *(const bf16x8*)(Als + (wm + m * 16 + lrow) * 32 + kseg);
#pragma unroll
        for (int n = 0; n < 4; ++n)
            bv[n] = *(const bf16x8*)(Bls + (wn + n * 16 + lrow) * 32 + kseg);
#pragma unroll
        for (int m = 0; m < 4; ++m)
#pragma unroll
            for (int n = 0; n < 4; ++n)
                acc[m][n] = __builtin_amdgcn_mfma_f32_16x16x32_bf16(
                    af[m], bv[n], acc[m][n], 0, 0, 0);
        __syncthreads();
    }

    // epilogue: bias add, bf16 store, fused rn += sum(phi^2)
    float bsv[4];
#pragma unroll
    for (int n = 0; n < 4; ++n) bsv[n] = bias[n0 + wn + n * 16 + lrow];
#pragma unroll
    for (int m = 0; m < 4; ++m) {
        float rsum[4] = {0.f, 0.f, 0.f, 0.f};
#pragma unroll
        for (int n = 0; n < 4; ++n) {
            int col = n0 + wn + n * 16 + lrow;
            f32x4 v = acc[m][n];
#pragma unroll
            for (int i = 0; i < 4; ++i) {
                float f = v[i] + bsv[n];
                rsum[i] += f * f;
                int row = r0 + wm + m * 16 + rsub + i;
                out[(size_t)row * ldo + col] = f2bf(f);
            }
        }
#pragma unroll
        for (int i = 0; i < 4; ++i) {
            float s = rsum[i];
#pragma unroll
            for (int off = 1; off < 16; off <<= 1) s += __shfl_xor(s, off);
            if (lrow == 0)
                atomicAdd(&rn[r0 + wm + m * 16 + rsub + i], s);
        }
    }
}

// ---- GEMM2 + fused top-3 (lean epilogue, no LDS/no post-loop barrier) -----
// t[row][col] = cn[col] - 2 * sum_k phibf[row][k]*CTbf[col][k]
// Per (row, wn-half): in-wave 16-lane butterfly -> lrow==0 stores one float4
// triple to ptop2[(row*NPT2+pt)*2 + wnh]. Merge happens in final_kernel.
__global__ __launch_bounds__(256) void gemm_top3_kernel(
    const u16* __restrict__ A, const u16* __restrict__ B,
    const float* __restrict__ cn, float4* __restrict__ ptop2)
{
    __shared__ __align__(16) u16 Als[128 * 32];
    __shared__ __align__(16) u16 Bls[128 * 32];
    const int tid  = threadIdx.x;
    const int wid  = tid >> 6;
    const int lane = tid & 63;
    const int r0 = blockIdx.x * 128;
    const int pt = blockIdx.y;
    const int n0 = pt * 128;

    const int srow = lane >> 2;
    const int sseg = (lane & 3) * 8;
    const u16* Ag = A + (size_t)(r0 + wid * 32 + srow) * DIMC + sseg;
    const u16* Bg = B + (size_t)(n0 + wid * 32 + srow) * DIMC + sseg;
    u16* AlsW = Als + wid * 1024;
    u16* BlsW = Bls + wid * 1024;

    const int wm = (wid >> 1) * 64;
    const int wn = (wid & 1) * 64;
    const int wnh = wid & 1;
    const int lrow = lane & 15;
    const int kseg = (lane >> 4) * 8;
    const int rsub = (lane >> 4) * 4;

    // preload cn for this lane's 4 columns BEFORE the K-loop (overlaps loop)
    float cnv[4];
#pragma unroll
    for (int n = 0; n < 4; ++n) {
        int col = n0 + wn + n * 16 + lrow;
        cnv[n] = (col < NPROT) ? cn[col] : FLT_MAX;   // padded cols never win
    }

    f32x4 acc[4][4];
#pragma unroll
    for (int m = 0; m < 4; ++m)
#pragma unroll
        for (int n = 0; n < 4; ++n)
            acc[m][n] = (f32x4){0.f, 0.f, 0.f, 0.f};

    for (int k0 = 0; k0 < DIMC; k0 += 32) {
        gload_lds16(Ag + k0,                      AlsW);
        gload_lds16(Ag + (size_t)16 * DIMC + k0,  AlsW + 512);
        gload_lds16(Bg + k0,                      BlsW);
        gload_lds16(Bg + (size_t)16 * DIMC + k0,  BlsW + 512);
        __syncthreads();
        bf16x8 af[4], bv[4];
#pragma unroll
        for (int m = 0; m < 4; ++m)
            af[m] = *(const bf16x8*)(Als + (wm + m * 16 + lrow) * 32 + kseg);
#pragma unroll
        for (int n = 0; n < 4; ++n)
            bv[n] = *(const bf16x8*)(Bls + (wn + n * 16 + lrow) * 32 + kseg);
#pragma unroll
        for (int m = 0; m < 4; ++m)
#pragma unroll
            for (int n = 0; n < 4; ++n)
                acc[m][n] = __builtin_amdgcn_mfma_f32_16x16x32_bf16(
                    af[m], bv[n], acc[m][n], 0, 0, 0);
        __syncthreads();
    }

    // lean fused epilogue: register top3 + in-wave butterfly + global store
#pragma unroll
    for (int m = 0; m < 4; ++m) {
#pragma unroll
        for (int i = 0; i < 4; ++i) {
            float t0 = FLT_MAX, t1 = FLT_MAX, t2 = FLT_MAX;
#pragma unroll
            for (int n = 0; n < 4; ++n)
                ins3(cnv[n] - 2.f * acc[m][n][i], t0, t1, t2);
#pragma unroll
            for (int off = 1; off < 16; off <<= 1) {
                float s0 = __shfl_xor(t0, off);
                float s1 = __shfl_xor(t1, off);
                float s2 = __shfl_xor(t2, off);
                ins3(s0, t0, t1, t2);
                ins3(s1, t0, t1, t2);
                ins3(s2, t0, t1, t2);
            }
            if (lrow == 0) {
                int row = r0 + wm + m * 16 + rsub + i;
                ptop2[((size_t)row * NPT2 + pt) * 2 + wnh] =
                    make_float4(t0, t1, t2, FLT_MAX);
            }
        }
    }
}

// ---- final: merge 25x2 triples per row + sqrt + softmin (wave per row) ----
__global__ void final_kernel(const float4* __restrict__ ptop2,
                             const float* __restrict__ rn,
                             float* __restrict__ out) {
    int row  = blockIdx.x * 4 + (threadIdx.x >> 6);
    int lane = threadIdx.x & 63;
    float t0 = FLT_MAX, t1 = FLT_MAX, t2 = FLT_MAX;
    if (lane < NPT2 * 2) {
        float4 v = ptop2[(size_t)row * NPT2 * 2 + lane];
        t0 = v.x; t1 = v.y; t2 = v.z;
    }
#pragma unroll
    for (int off = 32; off > 0; off >>= 1) {
        float s0 = __shfl_xor(t0, off);
        float s1 = __shfl_xor(t1, off);
        float s2 = __shfl_xor(t2, off);
        ins3(s0, t0, t1, t2);
        ins3(s1, t0, t1, t2);
        ins3(s2, t0, t1, t2);
    }
    if (lane == 0) {
        float rv = rn[row];
        float d0 = sqrtf(rv + t0), d1 = sqrtf(rv + t1), d2 = sqrtf(rv + t2);
        float w0 = 1.f / (1.f + expf(d0 - d1) + expf(d0 - d2));
        out[row] = w0 * d0;
    }
}

extern "C" void kernel_launch(void* const* d_in, const int* in_sizes, int n_in,
                              void* d_out, int out_size, void* d_ws, size_t ws_size,
                              hipStream_t stream) {
    const float* p    = (const float*)d_in[0];
    const float* W    = (const float*)d_in[1];
    const float* bias = (const float*)d_in[2];
    const float* C    = (const float*)d_in[3];
    float* out = (float*)d_out;

    char* w = (char*)d_ws;
    u16* Pbf   = (u16*)w;  w += (size_t)MROWS * DIMC * 2;   // 45.0 MB
    u16* Wbf   = (u16*)w;  w += (size_t)DIMC * DIMC * 2;    //  6.4 MB
    u16* CTbf  = (u16*)w;  w += (size_t)NPAD * DIMC * 2;    // 11.5 MB
    u16* phibf = (u16*)w;  w += (size_t)MROWS * DIMC * 2;   // 45.0 MB
    float4* ptop2 = (float4*)w; w += (size_t)MROWS * NPT2 * 2 * 16;  // 10.0 MB
    float* cn  = (float*)w; w += (size_t)NPROT * 4;
    float* rn  = (float*)w;                                  // total ~118 MB

    // zero the atomic accumulators (cn and rn are adjacent)
    hipMemsetAsync(cn, 0, (NPROT + MROWS) * sizeof(float), stream);

    pack_p_kernel<<<dim3(HWSZ / 32, DIMC / 32, BATCH), 256, 0, stream>>>(p, Pbf);
    pack_w_kernel<<<(DIMC * DIMC / 4) / 256, 256, 0, stream>>>(W, Wbf);
    pack_c_kernel<<<dim3(NPROT / 32, DIMC / 32), 256, 0, stream>>>(C, CTbf, cn);

    gemm_bias_kernel<<<dim3(MROWS / 128, DIMC / 128), 256, 0, stream>>>(
        Pbf, Wbf, bias, phibf, DIMC, rn);
    gemm_top3_kernel<<<dim3(MROWS / 128, NPT2), 256, 0, stream>>>(
        phibf, CTbf, cn, ptop2);
    final_kernel<<<MROWS / 4, 256, 0, stream>>>(ptop2, rn, out);
}

// Round 11
// 681.824 us; speedup vs baseline: 1.1804x; 1.1699x over previous
//
#include <hip/hip_runtime.h>
#include <hip/hip_bf16.h>
#include <cfloat>

#define BATCH 4
#define DIMC 1792
#define HWSZ 3136
#define NPROT 3136
#define NPAD 3328           // NPROT padded to a multiple of 256
#define MROWS 12544
#define NKT 28              // DIMC/64 K-tiles

typedef unsigned short u16;
typedef unsigned int u32;
using bf16x8 = __attribute__((ext_vector_type(8))) short;
using f32x4  = __attribute__((ext_vector_type(4))) float;

__device__ __forceinline__ float bf2f(u32 u) { return __uint_as_float(u << 16); }
__device__ __forceinline__ u16 f2bf(float x) {
    __hip_bfloat16 h = __float2bfloat16(x);   // RNE
    return *reinterpret_cast<u16*>(&h);
}

// async global->LDS, 16B per lane; LDS dest = wave-uniform base + lane*16
__device__ __forceinline__ void gload_lds16(const u16* g, u16* l) {
    __builtin_amdgcn_global_load_lds(
        (const __attribute__((address_space(1))) void*)g,
        (__attribute__((address_space(3))) void*)l, 16, 0, 0);
}

__device__ __forceinline__ void ins3(float v, float& t0, float& t1, float& t2) {
    if (v < t2) {
        if (v < t1) {
            t2 = t1;
            if (v < t0) { t1 = t0; t0 = v; }
            else        { t1 = v; }
        } else {
            t2 = v;
        }
    }
}

// ---- pack p[b][c][hw] (fp32) -> Pbf[r=b*HWSZ+hw][c] (bf16) ----------------
__global__ void pack_p_kernel(const float* __restrict__ p, u16* __restrict__ Pbf) {
    __shared__ float tile[32][33];      // [c_local][hw_local]
    int hw0 = blockIdx.x * 32, c0 = blockIdx.y * 32, b = blockIdx.z;
    int tid = threadIdx.x;
    int tx = tid & 31, ty = tid >> 5;   // load: tx=hw, ty+j = c
#pragma unroll
    for (int j = 0; j < 32; j += 8)
        tile[ty + j][tx] = p[((size_t)(b * DIMC + c0 + ty + j)) * HWSZ + hw0 + tx];
    __syncthreads();
    int hwl = tid >> 3;                 // 0..31
    int c4  = (tid & 7) * 4;            // 0..28
    int r = b * HWSZ + hw0 + hwl;
    ushort4 o;
    o.x = f2bf(tile[c4 + 0][hwl]);
    o.y = f2bf(tile[c4 + 1][hwl]);
    o.z = f2bf(tile[c4 + 2][hwl]);
    o.w = f2bf(tile[c4 + 3][hwl]);
    *(ushort4*)(Pbf + (size_t)r * DIMC + c0 + c4) = o;
}

// ---- cast W[d][c] fp32 -> Wbf[d][c] bf16 ----------------------------------
__global__ void pack_w_kernel(const float* __restrict__ W, u16* __restrict__ Wbf) {
    size_t i = (size_t)(blockIdx.x * 256 + threadIdx.x) * 4;   // exact grid
    float4 v = *(const float4*)(W + i);
    ushort4 o;
    o.x = f2bf(v.x); o.y = f2bf(v.y); o.z = f2bf(v.z); o.w = f2bf(v.w);
    *(ushort4*)(Wbf + i) = o;
}

// ---- pack C[d][j] fp32 -> CTbf[j][d] bf16, fused cn[j] += sum_d C^2 -------
__global__ void pack_c_kernel(const float* __restrict__ C, u16* __restrict__ CTbf,
                              float* __restrict__ cn) {
    __shared__ float tile[32][33];      // [d_local][j_local]
    int j0 = blockIdx.x * 32, d0 = blockIdx.y * 32;
    int tid = threadIdx.x;
    int tx = tid & 31, ty = tid >> 5;
#pragma unroll
    for (int jj = 0; jj < 32; jj += 8)
        tile[ty + jj][tx] = C[(size_t)(d0 + ty + jj) * NPROT + j0 + tx];
    __syncthreads();
    int jl = tid >> 3;                  // 0..31
    int d4 = (tid & 7) * 4;
    float s = 0.f;
    ushort4 o;
    {
        float f0 = tile[d4 + 0][jl], f1 = tile[d4 + 1][jl];
        float f2 = tile[d4 + 2][jl], f3 = tile[d4 + 3][jl];
        o.x = f2bf(f0); o.y = f2bf(f1); o.z = f2bf(f2); o.w = f2bf(f3);
        s = f0 * f0 + f1 * f1 + f2 * f2 + f3 * f3;   // fp32, pre-rounding
    }
    *(ushort4*)(CTbf + (size_t)(j0 + jl) * DIMC + d0 + d4) = o;
#pragma unroll
    for (int off = 1; off < 8; off <<= 1) s += __shfl_xor(s, off);
    if ((tid & 7) == 0) atomicAdd(&cn[j0 + jl], s);
}

// ---- deep-pipelined 256x256 MFMA GEMM (T3+T4-lite) ------------------------
// out[r][n] = sum_k A[r][k]*B[n][k] (+bias[n]).  512 thr = 8 waves (2M x 4N),
// BK=64 split as 2x 32-k sub-tiles; LDS [buf][ks][256 rows][32 elems], 128KB.
// Counted vmcnt(8): next tile's 8 gload_lds stay in flight across barriers.
// Seg-swizzle: LDS seg slot s holds global seg s^(row&3)  (4-way not 8-way
// bank conflict); linear LDS dest + inverse-swizzled SOURCE + swizzled read.
// PLAIN store epilogue only (r6-r9: fused reduction epilogues stall 2.4x).
template<bool BIAS>
__global__ __launch_bounds__(512, 2) void gemm8_kernel(
    const u16* __restrict__ A, const u16* __restrict__ B,
    const float* __restrict__ bias, u16* __restrict__ out, int ldo)
{
    __shared__ __align__(16) u16 Als[4][256 * 32];   // [buf*2+ks]
    __shared__ __align__(16) u16 Bls[4][256 * 32];
    const int tid  = threadIdx.x;
    const int wid  = tid >> 6;
    const int lane = tid & 63;
    const int r0 = blockIdx.x * 256;
    const int n0 = blockIdx.y * 256;

    const int wm = (wid >> 2) * 128;    // wave row quadrant (0/128)
    const int wn = (wid & 3) * 64;      // wave col quadrant (0..192)
    const int lrow = lane & 15;
    const int rsub = (lane >> 4) * 4;
    // swizzled k-seg for frag reads: slot = (lane>>4) ^ (row&3), row&3==lrow&3
    const int kxor = (((lane >> 4) ^ (lrow & 3))) * 8;

    // staging geometry: flat 16B-chunk f in [0,1024): row=f>>2, slot=(f&3)
    // source seg = slot ^ (row&3)  (inverse of read swizzle; XOR involution)
    const int f1 = tid,       r1 = f1 >> 2, g1 = ((f1 & 3) ^ (r1 & 3)) * 8;
    const int f2 = tid + 512, r2 = f2 >> 2, g2 = ((f2 & 3) ^ (r2 & 3)) * 8;
    const u16* Abase = A + (size_t)r0 * DIMC;
    const u16* Bbase = B + (size_t)n0 * DIMC;
    const int wofs = wid * 512;         // u16; gload adds lane*16B

    f32x4 acc[8][4];
#pragma unroll
    for (int m = 0; m < 8; ++m)
#pragma unroll
        for (int n = 0; n < 4; ++n)
            acc[m][n] = (f32x4){0.f, 0.f, 0.f, 0.f};

    auto STAGE = [&](int t, int bf) {
        const u16* At = Abase + t * 64;
        const u16* Bt = Bbase + t * 64;
#pragma unroll
        for (int ks = 0; ks < 2; ++ks) {
            gload_lds16(At + (size_t)r1 * DIMC + ks * 32 + g1, &Als[bf * 2 + ks][wofs]);
            gload_lds16(At + (size_t)r2 * DIMC + ks * 32 + g2, &Als[bf * 2 + ks][4096 + wofs]);
            gload_lds16(Bt + (size_t)r1 * DIMC + ks * 32 + g1, &Bls[bf * 2 + ks][wofs]);
            gload_lds16(Bt + (size_t)r2 * DIMC + ks * 32 + g2, &Bls[bf * 2 + ks][4096 + wofs]);
        }
    };

    auto COMPUTE = [&](int bf) {
#pragma unroll
        for (int ks = 0; ks < 2; ++ks) {
            const u16* ab = Als[bf * 2 + ks];
            const u16* bb = Bls[bf * 2 + ks];
            bf16x8 af[8], bv[4];
#pragma unroll
            for (int m = 0; m < 8; ++m)
                af[m] = *(const bf16x8*)(ab + (wm + m * 16 + lrow) * 32 + kxor);
#pragma unroll
            for (int n = 0; n < 4; ++n)
                bv[n] = *(const bf16x8*)(bb + (wn + n * 16 + lrow) * 32 + kxor);
#pragma unroll
            for (int m = 0; m < 8; ++m)
#pragma unroll
                for (int n = 0; n < 4; ++n)
                    acc[m][n] = __builtin_amdgcn_mfma_f32_16x16x32_bf16(
                        af[m], bv[n], acc[m][n], 0, 0, 0);
        }
    };

    STAGE(0, 0);
    for (int t = 0; t < NKT - 1; ++t) {
        int bf = t & 1;
        STAGE(t + 1, bf ^ 1);               // 8 loads in flight across barrier
        __builtin_amdgcn_sched_barrier(0);
        asm volatile("s_waitcnt vmcnt(8)" ::: "memory");  // tile t landed
        __builtin_amdgcn_s_barrier();
        __builtin_amdgcn_sched_barrier(0);
        COMPUTE(bf);
        __builtin_amdgcn_sched_barrier(0);
        __builtin_amdgcn_s_barrier();       // all waves done reading buf bf
    }
    asm volatile("s_waitcnt vmcnt(0)" ::: "memory");      // last tile landed
    __builtin_amdgcn_s_barrier();
    COMPUTE((NKT - 1) & 1);

    // epilogue: C/D layout col=lane&15, row=(lane>>4)*4+i  [m89-verified]
#pragma unroll
    for (int n = 0; n < 4; ++n) {
        int col = n0 + wn + n * 16 + lrow;
        float bs = BIAS ? bias[col] : 0.f;
#pragma unroll
        for (int m = 0; m < 8; ++m) {
            f32x4 v = acc[m][n];
#pragma unroll
            for (int i = 0; i < 4; ++i) {
                int row = r0 + wm + m * 16 + rsub + i;
                out[(size_t)row * ldo + col] = f2bf(v[i] + bs);
            }
        }
    }
}

// ---- top-3 + rn + sqrt + softmin (wave per row) ---------------------------
__global__ void top3_final_kernel(const u16* __restrict__ fc,
                                  const u16* __restrict__ phibf,
                                  const float* __restrict__ cn,
                                  float* __restrict__ out) {
    int row  = blockIdx.x * 4 + (threadIdx.x >> 6);
    int lane = threadIdx.x & 63;

    // rn = sum_d phi[row][d]^2 (bf16 phi, fp32 accum)
    const u16* pr = phibf + (size_t)row * DIMC;
    float s = 0.f;
#pragma unroll
    for (int it = 0; it < 7; ++it) {
        uint2 v = *(const uint2*)(pr + (it * 64 + lane) * 4);
        float f0 = bf2f(v.x & 0xffffu), f1 = bf2f(v.x >> 16);
        float f2 = bf2f(v.y & 0xffffu), f3 = bf2f(v.y >> 16);
        s += f0 * f0 + f1 * f1 + f2 * f2 + f3 * f3;
    }
#pragma unroll
    for (int off = 32; off > 0; off >>= 1) s += __shfl_down(s, off);
    // lane 0 holds rv

    // top3 of cn[j] - 2*fc[row][j]
    const u16* fr = fc + (size_t)row * NPAD;
    float t0 = FLT_MAX, t1 = FLT_MAX, t2 = FLT_MAX;
#pragma unroll
    for (int it = 0; it < 6; ++it) {        // 6*512 = 3072 prototypes
        int j0 = (it * 64 + lane) * 8;
        uint4 v = *(const uint4*)(fr + j0);
        u32 wd[4] = {v.x, v.y, v.z, v.w};
#pragma unroll
        for (int e = 0; e < 4; ++e) {
            float flo = bf2f(wd[e] & 0xffffu);
            float fhi = bf2f(wd[e] >> 16);
            ins3(cn[j0 + 2 * e]     - 2.f * flo, t0, t1, t2);
            ins3(cn[j0 + 2 * e + 1] - 2.f * fhi, t0, t1, t2);
        }
    }
    {   // tail: prototypes 3072..3135
        int j = 3072 + lane;
        ins3(cn[j] - 2.f * bf2f((u32)fr[j]), t0, t1, t2);
    }
#pragma unroll
    for (int off = 32; off > 0; off >>= 1) {
        float s0 = __shfl_xor(t0, off);
        float s1 = __shfl_xor(t1, off);
        float s2 = __shfl_xor(t2, off);
        ins3(s0, t0, t1, t2);
        ins3(s1, t0, t1, t2);
        ins3(s2, t0, t1, t2);
    }
    if (lane == 0) {
        float rv = s;
        float d0 = sqrtf(rv + t0), d1 = sqrtf(rv + t1), d2 = sqrtf(rv + t2);
        float w0 = 1.f / (1.f + expf(d0 - d1) + expf(d0 - d2));
        out[row] = w0 * d0;
    }
}

extern "C" void kernel_launch(void* const* d_in, const int* in_sizes, int n_in,
                              void* d_out, int out_size, void* d_ws, size_t ws_size,
                              hipStream_t stream) {
    const float* p    = (const float*)d_in[0];
    const float* W    = (const float*)d_in[1];
    const float* bias = (const float*)d_in[2];
    const float* C    = (const float*)d_in[3];
    float* out = (float*)d_out;

    char* w = (char*)d_ws;
    u16* Pbf   = (u16*)w;  w += (size_t)MROWS * DIMC * 2;   // 45.0 MB
    u16* Wbf   = (u16*)w;  w += (size_t)DIMC * DIMC * 2;    //  6.4 MB
    u16* CTbf  = (u16*)w;  w += (size_t)NPAD * DIMC * 2;    // 11.9 MB
    u16* phibf = (u16*)w;  w += (size_t)MROWS * DIMC * 2;   // 45.0 MB
    u16* fc    = (u16*)w;  w += (size_t)MROWS * NPAD * 2;   // 83.5 MB
    float* cn  = (float*)w;                                  // total ~191.8 MB

    hipMemsetAsync(cn, 0, NPROT * sizeof(float), stream);

    pack_p_kernel<<<dim3(HWSZ / 32, DIMC / 32, BATCH), 256, 0, stream>>>(p, Pbf);
    pack_w_kernel<<<(DIMC * DIMC / 4) / 256, 256, 0, stream>>>(W, Wbf);
    pack_c_kernel<<<dim3(NPROT / 32, DIMC / 32), 256, 0, stream>>>(C, CTbf, cn);

    gemm8_kernel<true><<<dim3(MROWS / 256, DIMC / 256), 512, 0, stream>>>(
        Pbf, Wbf, bias, phibf, DIMC);
    gemm8_kernel<false><<<dim3(MROWS / 256, NPAD / 256), 512, 0, stream>>>(
        phibf, CTbf, nullptr, fc, NPAD);
    top3_final_kernel<<<MROWS / 4, 256, 0, stream>>>(fc, phibf, cn, out);
}